// Round 4
// baseline (282.685 us; speedup 1.0000x reference)
//
#include <hip/hip_runtime.h>
#include <stdint.h>

#define SEQ   4096
#define EMB   1024
#define HD    128
#define WIN   256
#define MROWS 8192   // SEQ*B

typedef unsigned short u16;
typedef unsigned long long u64;
typedef __bf16 v8bf  __attribute__((ext_vector_type(8)));
typedef float  v4f   __attribute__((ext_vector_type(4)));
typedef u16    v8u16 __attribute__((ext_vector_type(8)));

__device__ __forceinline__ u16 f2bf(float f) {
  uint32_t u = __builtin_bit_cast(uint32_t, f);
  u += 0x7FFFu + ((u >> 16) & 1u);
  return (u16)(u >> 16);
}
__device__ __forceinline__ void gl_lds16(const u16* g, u16* l) {
  __builtin_amdgcn_global_load_lds((const __attribute__((address_space(1))) void*)g,
                                   (__attribute__((address_space(3))) void*)l,
                                   16, 0, 0);
}

// ---------------------------------------------------------------------------
// f32 -> bf16 conversion: val (8.4M) and Wq/Wk/Wv (1M each) into workspace.
// ---------------------------------------------------------------------------
__global__ __launch_bounds__(256)
void cvt_f32_bf16(const float* __restrict__ val,
                  const float* __restrict__ Wq,
                  const float* __restrict__ Wk,
                  const float* __restrict__ Wv,
                  u16* __restrict__ valbf, u16* __restrict__ Wbf)
{
  const int seg = blockIdx.y;
  const float* src; u16* dst; int nblk;
  if (seg == 0)      { src = val; dst = valbf;              nblk = 4096; }
  else if (seg == 1) { src = Wq;  dst = Wbf;                nblk = 512;  }
  else if (seg == 2) { src = Wk;  dst = Wbf + (1u << 20);   nblk = 512;  }
  else               { src = Wv;  dst = Wbf + (2u << 20);   nblk = 512;  }
  if ((int)blockIdx.x >= nblk) return;
  const int t = blockIdx.x * 256 + threadIdx.x;   // 8 elems per thread
  float4 a = ((const float4*)src)[2 * t];
  float4 b = ((const float4*)src)[2 * t + 1];
  v8u16 o;
  o[0] = f2bf(a.x); o[1] = f2bf(a.y); o[2] = f2bf(a.z); o[3] = f2bf(a.w);
  o[4] = f2bf(b.x); o[5] = f2bf(b.y); o[6] = f2bf(b.z); o[7] = f2bf(b.w);
  ((v8u16*)dst)[t] = o;
}

// ---------------------------------------------------------------------------
// Fused QKV GEMM. Q/K row-major (attention order); V stored TRANSPOSED as
// VT[(b*8+h)*128 + d][s]. Grid: bm fastest (x) so same A-slab => same XCD.
// ---------------------------------------------------------------------------
__global__ __launch_bounds__(256, 3)
void qkv_gemm(const u16* __restrict__ valbf, const u16* __restrict__ Wbf,
              const float* __restrict__ bq, const float* __restrict__ bk,
              const float* __restrict__ bv,
              u16* __restrict__ Qb, u16* __restrict__ Kb, u16* __restrict__ VTg)
{
  __shared__ __align__(16) u16 As[128 * 64];
  __shared__ __align__(16) u16 Bs[128 * 64];

  const int tid  = threadIdx.x;
  const int lane = tid & 63;
  const int w    = tid >> 6;
  const int quad = lane >> 4;
  const int lq   = lane & 15;
  const int wm   = w >> 1, wn = w & 1;

  const int bm = blockIdx.x;   // 0..63  (fastest -> XCD-local A slab)
  const int bn = blockIdx.y;   // 0..23

  const int seg = bn >> 3;     // 0=Q 1=K 2=V
  const u16*   Wsel = Wbf + (size_t)seg * EMB * EMB;
  const float* bsel = seg == 0 ? bq : (seg == 1 ? bk : bv);
  const int nseg0 = (bn & 7) * 128;

  const u16* arow[4];
  const u16* brow[4];
#pragma unroll
  for (int call = 0; call < 4; ++call) {
    int c  = call * 256 + w * 64 + lane;
    int m  = c >> 3;
    int qs = c & 7;
    int q  = qs ^ (m & 7);
    int a2 = bm * 128 + m;
    int aa = 2 * (a2 & 4095) + (a2 >> 12);
    int grow = (aa & 4095) * 2 + (aa >> 12);
    arow[call] = valbf + (size_t)grow * EMB + q * 8;
    int n = nseg0 + m;
    brow[call] = Wsel + (size_t)n * EMB + q * 8;
  }

  v4f acc[4][4];
#pragma unroll
  for (int mt = 0; mt < 4; ++mt)
#pragma unroll
    for (int nt = 0; nt < 4; ++nt) acc[mt][nt] = (v4f){0.f, 0.f, 0.f, 0.f};

#pragma unroll 1
  for (int kt = 0; kt < 16; ++kt) {
    const int k0 = kt * 64;
    __syncthreads();
#pragma unroll
    for (int call = 0; call < 4; ++call) {
      gl_lds16(arow[call] + k0, &As[(call * 256 + w * 64) * 8]);
      gl_lds16(brow[call] + k0, &Bs[(call * 256 + w * 64) * 8]);
    }
    __syncthreads();
#pragma unroll
    for (int ks = 0; ks < 2; ++ks) {
      v8bf afr[4], bfr[4];
      const int qa = ks * 4 + quad;
#pragma unroll
      for (int mt = 0; mt < 4; ++mt) {
        int m = wm * 64 + mt * 16 + lq;
        afr[mt] = *(const v8bf*)&As[(m * 8 + (qa ^ (m & 7))) * 8];
      }
#pragma unroll
      for (int nt = 0; nt < 4; ++nt) {
        int n = wn * 64 + nt * 16 + lq;
        bfr[nt] = *(const v8bf*)&Bs[(n * 8 + (qa ^ (n & 7))) * 8];
      }
#pragma unroll
      for (int mt = 0; mt < 4; ++mt)
#pragma unroll
        for (int nt = 0; nt < 4; ++nt)
          acc[mt][nt] = __builtin_amdgcn_mfma_f32_16x16x32_bf16(afr[mt], bfr[nt], acc[mt][nt], 0, 0, 0);
    }
  }

  const float scale = 0.08838834764831845f;  // 1/sqrt(128)
  float bias[4];
#pragma unroll
  for (int nt = 0; nt < 4; ++nt)
    bias[nt] = bsel[nseg0 + wn * 64 + nt * 16 + lq];

  if (seg == 2) {
    // V: store transposed, 4 m-consecutive values packed per 8B store
    const int h  = bn & 7;
    const int bp = bm >> 5;
    const int s0 = (bm & 31) * 128;
#pragma unroll
    for (int mt = 0; mt < 4; ++mt) {
      int mb = wm * 64 + mt * 16 + quad * 4;
#pragma unroll
      for (int nt = 0; nt < 4; ++nt) {
        int n = wn * 64 + nt * 16 + lq;   // = d (0..127)
        u64 pk = 0;
#pragma unroll
        for (int r = 0; r < 4; ++r)
          pk |= (u64)f2bf(acc[mt][nt][r] + bias[nt]) << (16 * r);
        *(u64*)&VTg[((size_t)(bp * 8 + h) * HD + n) * SEQ + s0 + mb] = pk;
      }
    }
  } else {
    u16* Osel = (seg == 0) ? Qb : Kb;
#pragma unroll
    for (int mt = 0; mt < 4; ++mt) {
      int rbase = bm * 128 + wm * 64 + mt * 16 + quad * 4;
#pragma unroll
      for (int nt = 0; nt < 4; ++nt) {
        int ncol = nseg0 + wn * 64 + nt * 16 + lq;
#pragma unroll
        for (int r = 0; r < 4; ++r) {
          float v = acc[mt][nt][r] + bias[nt];
          if (seg == 0) v *= scale;
          Osel[(size_t)(rbase + r) * EMB + ncol] = f2bf(v);
        }
      }
    }
  }
}

// ---------------------------------------------------------------------------
// Banded attention — BARRIER-FREE. K and V^T fragments read straight from
// global (L1/L2-cached; per-iter working set 32 KB fits L1). K frags register-
// pipelined one key-block ahead; V frags issued early each iteration. P
// roundtrip via wave-private LDS (no sync). Zero-shift softmax (scores O(1));
// padding = exp(0)=1 added in finalize. Mask only on the 2 extreme band tiles.
// ---------------------------------------------------------------------------
__global__ __launch_bounds__(256, 2)
void local_attn(const u16* __restrict__ Qb, const u16* __restrict__ Kb,
                const u16* __restrict__ VTg, float* __restrict__ out)
{
  __shared__ __align__(16) u16 sP[4][16 * 72];   // per-wave P tile

  const int tid  = threadIdx.x;
  const int lane = tid & 63;
  const int w    = tid >> 6;
  const int quad = lane >> 4;
  const int lq   = lane & 15;

  const int bh = blockIdx.x;        // b'*8 + h
  const int q0 = blockIdx.y * 64;
  const int bp = bh >> 3;
  const int h  = bh & 7;
  const size_t rowbase = (size_t)bp * SEQ;

  // Q A-fragments (pre-scaled in GEMM)
  v8bf qf[4];
  {
    const u16* qrow = Qb + (rowbase + q0 + w * 16 + lq) * EMB + h * HD;
#pragma unroll
    for (int ks = 0; ks < 4; ++ks)
      qf[ks] = *(const v8bf*)(qrow + ks * 32 + quad * 8);
  }

  v4f oacc[8];
#pragma unroll
  for (int dt = 0; dt < 8; ++dt) oacc[dt] = (v4f){0.f, 0.f, 0.f, 0.f};
  float ls[4] = {0.f, 0.f, 0.f, 0.f};

  const int jlo = (q0 - WIN > 0) ? q0 - WIN : 0;
  const int jhi = (q0 + 64 + WIN < SEQ) ? q0 + 64 + WIN : SEQ;
  const int nit = (jhi - jlo) >> 6;

  const u16* Kbase = Kb + rowbase * EMB + h * HD;       // + k*EMB
  const u16* Vbase = VTg + (size_t)bh * HD * SEQ;       // + d*SEQ

  // prefetch K frags for iter 0
  v8bf kfc[4][4];
#pragma unroll
  for (int ks = 0; ks < 4; ++ks)
#pragma unroll
    for (int nt = 0; nt < 4; ++nt)
      kfc[ks][nt] = *(const v8bf*)(Kbase + (size_t)(jlo + nt * 16 + lq) * EMB
                                   + ks * 32 + quad * 8);

#pragma unroll 1
  for (int it = 0; it < nit; ++it) {
    const int kb  = jlo + it * 64;
    const int kbn = (it + 1 < nit) ? kb + 64 : jlo;   // clamped dummy on last

    // --- S = Q K^T; refill kfc for next block right after each use ---
    v4f sfr[4];
#pragma unroll
    for (int nt = 0; nt < 4; ++nt) sfr[nt] = (v4f){0.f, 0.f, 0.f, 0.f};
#pragma unroll
    for (int ks = 0; ks < 4; ++ks) {
#pragma unroll
      for (int nt = 0; nt < 4; ++nt)
        sfr[nt] = __builtin_amdgcn_mfma_f32_16x16x32_bf16(qf[ks], kfc[ks][nt], sfr[nt], 0, 0, 0);
#pragma unroll
      for (int nt = 0; nt < 4; ++nt)
        kfc[ks][nt] = *(const v8bf*)(Kbase + (size_t)(kbn + nt * 16 + lq) * EMB
                                     + ks * 32 + quad * 8);
    }

    // --- V^T B-frags for THIS iter, issued early (covered by softmax VALU) ---
    v8bf vfc[2][8];
#pragma unroll
    for (int kv = 0; kv < 2; ++kv)
#pragma unroll
      for (int dt = 0; dt < 8; ++dt)
        vfc[kv][dt] = *(const v8bf*)(Vbase + (size_t)(dt * 16 + lq) * SEQ
                                     + kb + kv * 32 + quad * 8);

    // --- exp (no shift) + mask (only extreme tiles) + denom + P to LDS ---
    const bool need_mask = (kb == q0 - 256) || (kb == q0 + 256);
#pragma unroll
    for (int nt = 0; nt < 4; ++nt) {
#pragma unroll
      for (int r = 0; r < 4; ++r) {
        float pv = __expf(sfr[nt][r]);
        if (need_mask) {
          int j  = kb + nt * 16 + lq;
          int sr = q0 + w * 16 + quad * 4 + r;
          int dd = j - sr;
          pv = (dd <= WIN && dd >= -WIN) ? pv : 0.f;
        }
        ls[r] += pv;
        sP[w][(quad * 4 + r) * 72 + nt * 16 + lq] = f2bf(pv);
      }
    }

    // --- O += P V (wave-private sP: no barrier, lgkmcnt only) ---
#pragma unroll
    for (int kv = 0; kv < 2; ++kv) {
      v8bf pf = *(const v8bf*)&sP[w][lq * 72 + kv * 32 + quad * 8];
#pragma unroll
      for (int dt = 0; dt < 8; ++dt)
        oacc[dt] = __builtin_amdgcn_mfma_f32_16x16x32_bf16(pf, vfc[kv][dt], oacc[dt], 0, 0, 0);
    }
  }

  // --- finalize: reduce denominators, add zero-padding count, store ---
  float lrow[4];
#pragma unroll
  for (int r = 0; r < 4; ++r) {
    float t = ls[r];
#pragma unroll
    for (int off = 1; off < 16; off <<= 1) t += __shfl_xor(t, off);
    int sr = q0 + w * 16 + quad * 4 + r;
    int npl = WIN - sr;             if (npl < 0) npl = 0;
    int npr = sr - (SEQ - 1 - WIN); if (npr < 0) npr = 0;
    lrow[r] = t + (float)(npl + npr);
  }
#pragma unroll
  for (int dt = 0; dt < 8; ++dt) {
#pragma unroll
    for (int r = 0; r < 4; ++r) {
      int sr = q0 + w * 16 + quad * 4 + r;
      out[(size_t)(2 * sr + bp) * EMB + h * HD + dt * 16 + lq] = oacc[dt][r] / lrow[r];
    }
  }
}

extern "C" void kernel_launch(void* const* d_in, const int* in_sizes, int n_in,
                              void* d_out, int out_size, void* d_ws, size_t ws_size,
                              hipStream_t stream) {
  const float* val = (const float*)d_in[0];
  const float* bq  = (const float*)d_in[2];
  const float* bk  = (const float*)d_in[4];
  const float* bv  = (const float*)d_in[6];
  float* out = (float*)d_out;

  u16* valbf = (u16*)d_ws;                              // 8192*1024
  u16* Wbf   = valbf + (size_t)MROWS * EMB;             // 3*1024*1024
  u16* Qb    = Wbf + (size_t)3 * EMB * EMB;
  u16* Kb    = Qb + (size_t)MROWS * EMB;
  u16* VTg   = Kb + (size_t)MROWS * EMB;                // [b*8+h][128 d][4096 s]

  hipLaunchKernelGGL(cvt_f32_bf16, dim3(4096, 4), dim3(256), 0, stream,
                     val, (const float*)d_in[1], (const float*)d_in[3],
                     (const float*)d_in[5], valbf, Wbf);
  hipLaunchKernelGGL(qkv_gemm, dim3(64, 24), dim3(256), 0, stream,
                     valbf, Wbf, bq, bk, bv, Qb, Kb, VTg);
  hipLaunchKernelGGL(local_attn, dim3(16, 64), dim3(256), 0, stream,
                     Qb, Kb, VTg, out);
}

// Round 5
// 188.733 us; speedup vs baseline: 1.4978x; 1.4978x over previous
//
#include <hip/hip_runtime.h>
#include <stdint.h>

#define SEQ   4096
#define EMB   1024
#define HD    128
#define WIN   256
#define MROWS 8192   // SEQ*B

typedef unsigned short u16;
typedef unsigned long long u64;
typedef __bf16 v8bf  __attribute__((ext_vector_type(8)));
typedef float  v4f   __attribute__((ext_vector_type(4)));
typedef u16    v8u16 __attribute__((ext_vector_type(8)));

__device__ __forceinline__ u16 f2bf(float f) {
  uint32_t u = __builtin_bit_cast(uint32_t, f);
  u += 0x7FFFu + ((u >> 16) & 1u);
  return (u16)(u >> 16);
}
__device__ __forceinline__ void gl_lds16(const u16* g, u16* l) {
  __builtin_amdgcn_global_load_lds((const __attribute__((address_space(1))) void*)g,
                                   (__attribute__((address_space(3))) void*)l,
                                   16, 0, 0);
}

// ---------------------------------------------------------------------------
// f32 -> bf16 conversion: val (8.4M) and Wq/Wk/Wv (1M each) into workspace.
// ---------------------------------------------------------------------------
__global__ __launch_bounds__(256)
void cvt_f32_bf16(const float* __restrict__ val,
                  const float* __restrict__ Wq,
                  const float* __restrict__ Wk,
                  const float* __restrict__ Wv,
                  u16* __restrict__ valbf, u16* __restrict__ Wbf)
{
  const int seg = blockIdx.y;
  const float* src; u16* dst; int nblk;
  if (seg == 0)      { src = val; dst = valbf;              nblk = 4096; }
  else if (seg == 1) { src = Wq;  dst = Wbf;                nblk = 512;  }
  else if (seg == 2) { src = Wk;  dst = Wbf + (1u << 20);   nblk = 512;  }
  else               { src = Wv;  dst = Wbf + (2u << 20);   nblk = 512;  }
  if ((int)blockIdx.x >= nblk) return;
  const int t = blockIdx.x * 256 + threadIdx.x;   // 8 elems per thread
  float4 a = ((const float4*)src)[2 * t];
  float4 b = ((const float4*)src)[2 * t + 1];
  v8u16 o;
  o[0] = f2bf(a.x); o[1] = f2bf(a.y); o[2] = f2bf(a.z); o[3] = f2bf(a.w);
  o[4] = f2bf(b.x); o[5] = f2bf(b.y); o[6] = f2bf(b.z); o[7] = f2bf(b.w);
  ((v8u16*)dst)[t] = o;
}

// ---------------------------------------------------------------------------
// Fused QKV GEMM. Q/K row-major (attention order); V stored TRANSPOSED as
// VT[(b*8+h)*128 + d][s]. Grid: bm fastest (x) so same A-slab => same XCD.
// ---------------------------------------------------------------------------
__global__ __launch_bounds__(256, 3)
void qkv_gemm(const u16* __restrict__ valbf, const u16* __restrict__ Wbf,
              const float* __restrict__ bq, const float* __restrict__ bk,
              const float* __restrict__ bv,
              u16* __restrict__ Qb, u16* __restrict__ Kb, u16* __restrict__ VTg)
{
  __shared__ __align__(16) u16 As[128 * 64];
  __shared__ __align__(16) u16 Bs[128 * 64];

  const int tid  = threadIdx.x;
  const int lane = tid & 63;
  const int w    = tid >> 6;
  const int quad = lane >> 4;
  const int lq   = lane & 15;
  const int wm   = w >> 1, wn = w & 1;

  const int bm = blockIdx.x;   // 0..63  (fastest -> XCD-local A slab)
  const int bn = blockIdx.y;   // 0..23

  const int seg = bn >> 3;     // 0=Q 1=K 2=V
  const u16*   Wsel = Wbf + (size_t)seg * EMB * EMB;
  const float* bsel = seg == 0 ? bq : (seg == 1 ? bk : bv);
  const int nseg0 = (bn & 7) * 128;

  const u16* arow[4];
  const u16* brow[4];
#pragma unroll
  for (int call = 0; call < 4; ++call) {
    int c  = call * 256 + w * 64 + lane;
    int m  = c >> 3;
    int qs = c & 7;
    int q  = qs ^ (m & 7);
    int a2 = bm * 128 + m;
    int aa = 2 * (a2 & 4095) + (a2 >> 12);
    int grow = (aa & 4095) * 2 + (aa >> 12);
    arow[call] = valbf + (size_t)grow * EMB + q * 8;
    int n = nseg0 + m;
    brow[call] = Wsel + (size_t)n * EMB + q * 8;
  }

  v4f acc[4][4];
#pragma unroll
  for (int mt = 0; mt < 4; ++mt)
#pragma unroll
    for (int nt = 0; nt < 4; ++nt) acc[mt][nt] = (v4f){0.f, 0.f, 0.f, 0.f};

#pragma unroll 1
  for (int kt = 0; kt < 16; ++kt) {
    const int k0 = kt * 64;
    __syncthreads();
#pragma unroll
    for (int call = 0; call < 4; ++call) {
      gl_lds16(arow[call] + k0, &As[(call * 256 + w * 64) * 8]);
      gl_lds16(brow[call] + k0, &Bs[(call * 256 + w * 64) * 8]);
    }
    __syncthreads();
#pragma unroll
    for (int ks = 0; ks < 2; ++ks) {
      v8bf afr[4], bfr[4];
      const int qa = ks * 4 + quad;
#pragma unroll
      for (int mt = 0; mt < 4; ++mt) {
        int m = wm * 64 + mt * 16 + lq;
        afr[mt] = *(const v8bf*)&As[(m * 8 + (qa ^ (m & 7))) * 8];
      }
#pragma unroll
      for (int nt = 0; nt < 4; ++nt) {
        int n = wn * 64 + nt * 16 + lq;
        bfr[nt] = *(const v8bf*)&Bs[(n * 8 + (qa ^ (n & 7))) * 8];
      }
#pragma unroll
      for (int mt = 0; mt < 4; ++mt)
#pragma unroll
        for (int nt = 0; nt < 4; ++nt)
          acc[mt][nt] = __builtin_amdgcn_mfma_f32_16x16x32_bf16(afr[mt], bfr[nt], acc[mt][nt], 0, 0, 0);
    }
  }

  const float scale = 0.08838834764831845f;  // 1/sqrt(128)
  float bias[4];
#pragma unroll
  for (int nt = 0; nt < 4; ++nt)
    bias[nt] = bsel[nseg0 + wn * 64 + nt * 16 + lq];

  if (seg == 2) {
    // V: store transposed, 4 m-consecutive values packed per 8B store
    const int h  = bn & 7;
    const int bp = bm >> 5;
    const int s0 = (bm & 31) * 128;
#pragma unroll
    for (int mt = 0; mt < 4; ++mt) {
      int mb = wm * 64 + mt * 16 + quad * 4;
#pragma unroll
      for (int nt = 0; nt < 4; ++nt) {
        int n = wn * 64 + nt * 16 + lq;   // = d (0..127)
        u64 pk = 0;
#pragma unroll
        for (int r = 0; r < 4; ++r)
          pk |= (u64)f2bf(acc[mt][nt][r] + bias[nt]) << (16 * r);
        *(u64*)&VTg[((size_t)(bp * 8 + h) * HD + n) * SEQ + s0 + mb] = pk;
      }
    }
  } else {
    u16* Osel = (seg == 0) ? Qb : Kb;
#pragma unroll
    for (int mt = 0; mt < 4; ++mt) {
      int rbase = bm * 128 + wm * 64 + mt * 16 + quad * 4;
#pragma unroll
      for (int nt = 0; nt < 4; ++nt) {
        int ncol = nseg0 + wn * 64 + nt * 16 + lq;
#pragma unroll
        for (int r = 0; r < 4; ++r) {
          float v = acc[mt][nt][r] + bias[nt];
          if (seg == 0) v *= scale;
          Osel[(size_t)(rbase + r) * EMB + ncol] = f2bf(v);
        }
      }
    }
  }
}

// ---------------------------------------------------------------------------
// Banded attention. BOTH K and V^T tiles staged in LDS via coalesced
// global_load_lds DMA (no scattered in-loop global loads), double-buffered,
// XOR-swizzled slots for conflict-balanced ds_read_b128 fragment reads.
// One barrier per key block; prefetch has a full iteration in flight.
// Zero-shift softmax; padding = exp(0)=1 added in finalize; band mask only
// on the two extreme tiles. P roundtrip via wave-private LDS (no barrier).
// ---------------------------------------------------------------------------
__global__ __launch_bounds__(256, 2)
void local_attn(const u16* __restrict__ Qb, const u16* __restrict__ Kb,
                const u16* __restrict__ VTg, float* __restrict__ out)
{
  __shared__ __align__(16) u16 sK [2][64 * 128];   // K tile  [j][d], swizzled
  __shared__ __align__(16) u16 sVT[2][128 * 64];   // V^T tile [d][j], swizzled
  __shared__ __align__(16) u16 sP [4][16 * 72];    // per-wave P tile

  const int tid  = threadIdx.x;
  const int lane = tid & 63;
  const int w    = tid >> 6;
  const int quad = lane >> 4;
  const int lq   = lane & 15;

  const int bh = blockIdx.x;        // b'*8 + h
  const int q0 = blockIdx.y * 64;
  const int bp = bh >> 3;
  const int h  = bh & 7;
  const size_t rowbase = (size_t)bp * SEQ;

  const u16* Kbase = Kb + rowbase * EMB + h * HD;       // + j*EMB
  const u16* Vbase = VTg + (size_t)bh * HD * SEQ;       // + d*SEQ

  // Q A-fragments (pre-scaled in GEMM); one-time scattered load
  v8bf qf[4];
  {
    const u16* qrow = Qb + (rowbase + q0 + w * 16 + lq) * EMB + h * HD;
#pragma unroll
    for (int ks = 0; ks < 4; ++ks)
      qf[ks] = *(const v8bf*)(qrow + ks * 32 + quad * 8);
  }

  v4f oacc[8];
#pragma unroll
  for (int dt = 0; dt < 8; ++dt) oacc[dt] = (v4f){0.f, 0.f, 0.f, 0.f};
  float ls[4] = {0.f, 0.f, 0.f, 0.f};

  const int jlo = (q0 - WIN > 0) ? q0 - WIN : 0;
  const int jhi = (q0 + 64 + WIN < SEQ) ? q0 + 64 + WIN : SEQ;
  const int nit = (jhi - jlo) >> 6;

  // coalesced DMA staging of one K tile (64x128) + one V^T tile (128x64)
  auto stage = [&](int kb, int p) {
#pragma unroll
    for (int call = 0; call < 4; ++call) {
      int s = call * 256 + w * 64 + lane;     // K slot (16B chunks)
      int row = s >> 4, sl = s & 15;
      int q = sl ^ (row & 15);
      gl_lds16(Kbase + (size_t)(kb + row) * EMB + q * 8,
               &sK[p][(call * 256 + w * 64) * 8]);
    }
#pragma unroll
    for (int call = 0; call < 4; ++call) {
      int s = call * 256 + w * 64 + lane;     // VT slot
      int d = s >> 3, sl = s & 7;
      int q = sl ^ (d & 7);
      gl_lds16(Vbase + (size_t)d * SEQ + kb + q * 8,
               &sVT[p][(call * 256 + w * 64) * 8]);
    }
  };

  stage(jlo, 0);   // prologue

#pragma unroll 1
  for (int it = 0; it < nit; ++it) {
    const int p  = it & 1;
    const int kb = jlo + it * 64;
    __syncthreads();                     // buf p DMA complete; buf p^1 free
    if (it + 1 < nit) stage(kb + 64, p ^ 1);

    // --- S = Q K^T from LDS ---
    v4f sfr[4];
#pragma unroll
    for (int nt = 0; nt < 4; ++nt) sfr[nt] = (v4f){0.f, 0.f, 0.f, 0.f};
#pragma unroll
    for (int ks = 0; ks < 4; ++ks) {
      const int sl = (ks * 4 + quad) ^ lq;
#pragma unroll
      for (int nt = 0; nt < 4; ++nt) {
        v8bf kf = *(const v8bf*)&sK[p][((nt * 16 + lq) * 16 + sl) * 8];
        sfr[nt] = __builtin_amdgcn_mfma_f32_16x16x32_bf16(qf[ks], kf, sfr[nt], 0, 0, 0);
      }
    }

    // --- exp (no shift) + mask (extreme tiles only) + denom + P to LDS ---
    const bool need_mask = (kb == q0 - 256) || (kb == q0 + 256);
#pragma unroll
    for (int nt = 0; nt < 4; ++nt) {
#pragma unroll
      for (int r = 0; r < 4; ++r) {
        float pv = __expf(sfr[nt][r]);
        if (need_mask) {
          int j  = kb + nt * 16 + lq;
          int sr = q0 + w * 16 + quad * 4 + r;
          int dd = j - sr;
          pv = (dd <= WIN && dd >= -WIN) ? pv : 0.f;
        }
        ls[r] += pv;
        sP[w][(quad * 4 + r) * 72 + nt * 16 + lq] = f2bf(pv);
      }
    }

    // --- O += P V from LDS (sP wave-private: no barrier) ---
#pragma unroll
    for (int kv = 0; kv < 2; ++kv) {
      v8bf pf = *(const v8bf*)&sP[w][lq * 72 + kv * 32 + quad * 8];
      const int slb = (kv * 4 + quad);
#pragma unroll
      for (int dt = 0; dt < 8; ++dt) {
        int d = dt * 16 + lq;
        v8bf vf = *(const v8bf*)&sVT[p][(d * 8 + (slb ^ (d & 7))) * 8];
        oacc[dt] = __builtin_amdgcn_mfma_f32_16x16x32_bf16(pf, vf, oacc[dt], 0, 0, 0);
      }
    }
  }

  // --- finalize: reduce denominators, add zero-padding count, store ---
  float lrow[4];
#pragma unroll
  for (int r = 0; r < 4; ++r) {
    float t = ls[r];
#pragma unroll
    for (int off = 1; off < 16; off <<= 1) t += __shfl_xor(t, off);
    int sr = q0 + w * 16 + quad * 4 + r;
    int npl = WIN - sr;             if (npl < 0) npl = 0;
    int npr = sr - (SEQ - 1 - WIN); if (npr < 0) npr = 0;
    lrow[r] = t + (float)(npl + npr);
  }
#pragma unroll
  for (int dt = 0; dt < 8; ++dt) {
#pragma unroll
    for (int r = 0; r < 4; ++r) {
      int sr = q0 + w * 16 + quad * 4 + r;
      out[(size_t)(2 * sr + bp) * EMB + h * HD + dt * 16 + lq] = oacc[dt][r] / lrow[r];
    }
  }
}

extern "C" void kernel_launch(void* const* d_in, const int* in_sizes, int n_in,
                              void* d_out, int out_size, void* d_ws, size_t ws_size,
                              hipStream_t stream) {
  const float* val = (const float*)d_in[0];
  const float* bq  = (const float*)d_in[2];
  const float* bk  = (const float*)d_in[4];
  const float* bv  = (const float*)d_in[6];
  float* out = (float*)d_out;

  u16* valbf = (u16*)d_ws;                              // 8192*1024
  u16* Wbf   = valbf + (size_t)MROWS * EMB;             // 3*1024*1024
  u16* Qb    = Wbf + (size_t)3 * EMB * EMB;
  u16* Kb    = Qb + (size_t)MROWS * EMB;
  u16* VTg   = Kb + (size_t)MROWS * EMB;                // [b*8+h][128 d][4096 s]

  hipLaunchKernelGGL(cvt_f32_bf16, dim3(4096, 4), dim3(256), 0, stream,
                     val, (const float*)d_in[1], (const float*)d_in[3],
                     (const float*)d_in[5], valbf, Wbf);
  hipLaunchKernelGGL(qkv_gemm, dim3(64, 24), dim3(256), 0, stream,
                     valbf, Wbf, bq, bk, bv, Qb, Kb, VTg);
  hipLaunchKernelGGL(local_attn, dim3(16, 64), dim3(256), 0, stream,
                     Qb, Kb, VTg, out);
}